// Round 11
// baseline (245.570 us; speedup 1.0000x reference)
//
#include <hip/hip_runtime.h>
#include <stdint.h>

#define NPTS  8192
#define NB    4
#define KNN   20
#define NROWS (NB * NPTS)        // 32768
#define NGROUPS (NROWS / 64)     // 512 row-groups
#define MTOTF 655360.0f          // NROWS * KNN
#define WPB   8                  // waves per block
#define BLK   (WPB * 64)         // 512 threads
#define SLICE (NPTS / WPB)       // fallback kernel slice
#define LSTR  (KNN + 1)
#define CAP   12                 // fallback push-buffer slots
#define CAP2  16                 // main push-buffer slots
#define NGRID (2 * NGROUPS)      // 1024 blocks = 512 groups x 2 sides
#define MAXPH (NPTS / 256)       // 32 phases = full side coverage (exactness cap)
#define NBIN  256
#define BINW  0.03125f           // 8/256
#define XLO   -4.0f
#define NEG_INF -3.0e38f

__device__ __forceinline__ float med3f(float a, float b, float c) {
    return __builtin_amdgcn_fmed3f(a, b, c);
}

// Monotone float<->uint encoding so LDS atomicMax works as float-max (any sign).
__device__ __forceinline__ unsigned enc_f(float f) {
    unsigned u = __float_as_uint(f);
    return (u & 0x80000000u) ? ~u : (u | 0x80000000u);
}
__device__ __forceinline__ float dec_f(unsigned u) {
    return __uint_as_float((u & 0x80000000u) ? (u & 0x7fffffffu) : ~u);
}

// Insert t into descending top-KNN list (arr[0] = largest t = nearest point).
// Dropping off the bottom is always exact: 20 larger witnesses exist.
__device__ __forceinline__ void insert_t(float arr[KNN], float t) {
#pragma unroll
    for (int j = KNN - 1; j > 0; --j) arr[j] = med3f(t, arr[j - 1], arr[j]);
    arr[0] = fmaxf(arr[0], t);
}

// ---- fallback flush: fixed CAP, padded ----
__device__ __forceinline__ void flush_buf(float arr[KNN], int& cnt,
    const float* bufw, int lane, unsigned* threshS) {
#pragma unroll
    for (int s = 0; s < CAP; ++s) {
        const float v = bufw[s * 64 + lane];
        insert_t(arr, (s < cnt) ? v : NEG_INF);
    }
    cnt = 0;
    atomicMax(&threshS[lane], enc_f(arr[KNN - 1]));
}

// ---- chunk-skippable flush (4 slots per uniform test), verified R2/R8 ----
__device__ __forceinline__ void flush_dyn(float arr[KNN], int& cnt,
    const float* bufw, int lane, unsigned* threshS) {
#pragma unroll
    for (int s0 = 0; s0 < CAP2; s0 += 4) {
        if (__any(cnt > s0)) {
#pragma unroll
            for (int s = s0; s < s0 + 4; ++s) {
                const float v = bufw[s * 64 + lane];
                insert_t(arr, (s < cnt) ? v : NEG_INF);
            }
        }
    }
    cnt = 0;
    atomicMax(&threshS[lane], enc_f(arr[KNN - 1]));
}

// Shared tail: caller holds merged descending-t list for output row `row`.
__device__ __forceinline__ void finalize_row(
    float arr[KNN], float px, float py, float pz, int row, int lane,
    float* __restrict__ kmaxA, float* __restrict__ kminA, float* __restrict__ acc)
{
    const float pn2 = px * px + py * py + pz * pz;
    float sum = 0.f, sum2 = 0.f, dmin = 0.f, dmax = 0.f;
#pragma unroll
    for (int k = 0; k < KNN; ++k) {
        float d2 = fmaxf(fmaf(-2.f, arr[k], pn2), 0.f);
        float d = sqrtf(d2);
        sum += d; sum2 += d2;
        if (k == 0) dmin = d;
        dmax = d;
    }
    kmaxA[row] = dmax;
    kminA[row] = dmin;
#pragma unroll
    for (int o = 32; o; o >>= 1) {
        sum  += __shfl_down(sum,  o, 64);
        sum2 += __shfl_down(sum2, o, 64);
    }
    if (lane == 0) { atomicAdd(acc, sum); atomicAdd(acc + 1, sum2); }
}

// ---- sort: bin by x (256 bins/batch), scatter to sorted order. 1 dispatch,
// replaces prep. Also zeroes acc + tickets. 4 blocks x 1024 threads.
__global__ __launch_bounds__(1024) void sort_kernel(
    const float* __restrict__ x, float4* __restrict__ sorted4,
    int* __restrict__ perm, float* __restrict__ acc, int* __restrict__ ticket)
{
    __shared__ int hist[NBIN];
    __shared__ int cursor[NBIN];
    const int b = blockIdx.x;
    const int tid = threadIdx.x;
    if (tid < NBIN) hist[tid] = 0;
    if (b == 0) {
        if (tid < 2) acc[tid] = 0.f;
        if (tid < NGROUPS) ticket[tid] = 0;
    }
    __syncthreads();
    const float* xb = x + b * 3 * NPTS;
    int bins[8];
#pragma unroll
    for (int k = 0; k < 8; ++k) {
        const int i = tid + k * 1024;
        int bin = (int)floorf((xb[i] - XLO) * 32.0f);
        bin = min(max(bin, 0), NBIN - 1);
        bins[k] = bin;
        atomicAdd(&hist[bin], 1);
    }
    __syncthreads();
    int cnt0 = (tid < NBIN) ? hist[tid] : 0;
    for (int off = 1; off < NBIN; off <<= 1) {
        int v = (tid < NBIN && tid >= off) ? hist[tid - off] : 0;
        __syncthreads();
        if (tid < NBIN) hist[tid] += v;
        __syncthreads();
    }
    if (tid < NBIN) cursor[tid] = hist[tid] - cnt0;   // exclusive start
    __syncthreads();
#pragma unroll
    for (int k = 0; k < 8; ++k) {
        const int i = tid + k * 1024;
        const float qx = xb[i];
        const float qy = xb[NPTS + i];
        const float qz = xb[2 * NPTS + i];
        const int pos = atomicAdd(&cursor[bins[k]], 1);
        sorted4[b * NPTS + pos] =
            make_float4(qx, qy, qz, -0.5f * (qx * qx + qy * qy + qz * qz));
        perm[b * NPTS + pos] = b * NPTS + i;
    }
}

// K1 (main): rows = 64 sorted-consecutive points. Sibling blocks split the
// batch by SIDE (indices >= group start vs < group start; disjoint, exact).
// Scan outward in dense 32-chunks (wave-uniform loads, no indirection).
// Early stop: DOUBLE-BARRIER uniform vote (R10 hang fix): tid0 pre-sets
// doneS=1 -> barrier (threshS now frozen: every thread is inside the vote
// region, no flush can run) -> waves compute vote, lane0s clear doneS ->
// barrier -> ALL threads read the same doneS -> break is block-uniform by
// construction regardless of inter-wave timing.
// Stop condition exact: threshold is a lower bound on the 20th t with >=20
// surviving witnesses -> d upper-bounds d20; unseen x beyond px+/-d can't
// enter the top-20. 32-phase cap = full side = exact fallback.
__global__ __launch_bounds__(BLK, 8) void knn_sorted_kernel(
    const float4* __restrict__ sorted4, const int* __restrict__ perm,
    float* __restrict__ part, int* __restrict__ ticket,
    float* __restrict__ kmaxA, float* __restrict__ kminA, float* __restrict__ acc)
{
    __shared__ float shmem[WPB * CAP2 * 64];   // 32 KB buffers; lists alias
    __shared__ unsigned threshS[64];
    __shared__ int doneS;

    const int tid  = threadIdx.x;
    const int lane = tid & 63;
    const int wave = __builtin_amdgcn_readfirstlane(tid >> 6);
    const int rb   = blockIdx.x >> 1;        // row-group 0..511
    const int side = blockIdx.x & 1;         // 0: indices >= base0; 1: < base0
    const int base0 = rb * 64;               // global sorted index of group start
    const int b    = base0 >> 13;
    const int batchBegin = b * NPTS;
    const int batchEnd   = batchBegin + NPTS;

    const float4 P = sorted4[base0 + lane];
    const float px = P.x, py = P.y, pz = P.z;
    const float pn2 = -2.f * P.w;

    if (tid < 64) threshS[tid] = enc_f(NEG_INF);

    float arr[KNN];
#pragma unroll
    for (int j = 0; j < KNN; ++j) arr[j] = NEG_INF;
    float* bufw = shmem + wave * (CAP2 * 64);
    int cnt = 0;
    __syncthreads();

    for (int p = 0; p < MAXPH; ++p) {
        const int ci = p * WPB + wave;
        const int cs = (side == 0) ? base0 + ci * 32 : base0 - (ci + 1) * 32;
        const bool valid = (side == 0) ? (cs < batchEnd) : (cs >= batchBegin);
        float th = dec_f(*(volatile unsigned*)(threshS + lane));
        if (valid) {
            const float4* tq = sorted4 + cs;
            for (int g = 0; g < 8; ++g) {
#pragma unroll
                for (int u = 0; u < 4; ++u) {
                    const float4 q = tq[g * 4 + u];   // wave-uniform scalar load
                    const float t = fmaf(q.x, px, fmaf(q.y, py, fmaf(q.z, pz, q.w)));
                    bufw[cnt * 64 + lane] = t;        // always-store (no branch)
                    cnt += (t > th);
                }
                if (__any(cnt > CAP2 - 4)) {
                    flush_dyn(arr, cnt, bufw, lane, threshS);
                    th = dec_f(*(volatile unsigned*)(threshS + lane));
                }
            }
        }
        if (tid == 0) doneS = 1;
        __syncthreads();   // flushes visible; threshS frozen until decision

        // per-wave vote (identical inputs across waves; AND-combined anyway)
        const float th2 = dec_f(*(volatile unsigned*)(threshS + lane));
        const float d2  = fmaxf(fmaf(-2.f, th2, pn2), 0.f);
        const float d   = sqrtf(d2);
        bool myDone;
        if (side == 0) {
            float need = px + d;                      // rightmost x still needed
#pragma unroll
            for (int o = 32; o; o >>= 1) need = fmaxf(need, __shfl_xor(need, o, 64));
            const int f = base0 + (p + 1) * 256;
            if (f >= batchEnd) myDone = true;
            else {
                const float xf = sorted4[f].x;
                int bf = (int)floorf((xf - XLO) * 32.0f);
                bf = min(max(bf, 0), NBIN - 1);
                // unseen right elems have bin >= bf -> x >= binLeft(bf); bin 0
                // may hold clamped x < XLO -> never stop on it.
                myDone = (bf > 0) && ((float)bf * BINW + XLO >= need);
            }
        } else {
            float need = px - d;                      // leftmost x still needed
#pragma unroll
            for (int o = 32; o; o >>= 1) need = fminf(need, __shfl_xor(need, o, 64));
            const int f = base0 - (p + 1) * 256;
            if (f <= batchBegin) myDone = true;
            else {
                const float xf = sorted4[f - 1].x;
                int bf = (int)floorf((xf - XLO) * 32.0f);
                bf = min(max(bf, 0), NBIN - 1);
                // unseen left elems have bin <= bf -> x <= binRight(bf); bin 255
                // may hold clamped x > XLO+8 -> never stop on it.
                myDone = (bf < NBIN - 1) && ((float)(bf + 1) * BINW + XLO <= need);
            }
        }
        if (lane == 0 && !myDone) doneS = 0;
        __syncthreads();   // decision now identical for every thread
        if (doneS) break;  // block-uniform break (hang fix)
    }
    if (__any(cnt > 0)) flush_dyn(arr, cnt, bufw, lane, threshS);
    __syncthreads();   // all push-buffer use done before aliased list writes

    // Tree merge (verified R4/R8): (0<-1)(2<-3)(4<-5)(6<-7) -> (0<-2)(4<-6) -> (0<-4)
    float* ml = shmem;
    if (wave & 1) {
        float* dl = ml + (wave >> 1) * (64 * LSTR) + lane * LSTR;
#pragma unroll
        for (int k = 0; k < KNN; ++k) dl[k] = arr[k];
    }
    __syncthreads();
    if (!(wave & 1)) {
        const float* s = ml + (wave >> 1) * (64 * LSTR) + lane * LSTR;
#pragma unroll
        for (int k = 0; k < KNN; ++k) insert_t(arr, s[k]);
    }
    __syncthreads();
    if (!(wave & 1) && (wave & 2)) {
        float* dl = ml + (wave >> 2) * (64 * LSTR) + lane * LSTR;
#pragma unroll
        for (int k = 0; k < KNN; ++k) dl[k] = arr[k];
    }
    __syncthreads();
    if ((wave & 3) == 0) {
        const float* s = ml + (wave >> 2) * (64 * LSTR) + lane * LSTR;
#pragma unroll
        for (int k = 0; k < KNN; ++k) insert_t(arr, s[k]);
    }
    __syncthreads();
    if (wave == 4) {
        float* dl = ml + lane * LSTR;
#pragma unroll
        for (int k = 0; k < KNN; ++k) dl[k] = arr[k];
    }
    __syncthreads();
    if (wave == 0) {
        const float* s = ml + lane * LSTR;
#pragma unroll
        for (int k = 0; k < KNN; ++k) insert_t(arr, s[k]);

        const int srow = base0 + lane;                // sorted row id (shared key)
        // publish sorted partial: sc1 relaxed agent stores (R8-verified, no wbl2/inv)
        float* dst = part + (srow * 2 + side) * KNN;
#pragma unroll
        for (int k = 0; k < KNN; ++k)
            __hip_atomic_store(&dst[k], arr[k], __ATOMIC_RELAXED,
                               __HIP_MEMORY_SCOPE_AGENT);
        asm volatile("s_waitcnt vmcnt(0)" ::: "memory");   // wave-local ordering

        int old = 0;
        if (lane == 0)
            old = __hip_atomic_fetch_add(&ticket[rb], 1, __ATOMIC_RELAXED,
                                         __HIP_MEMORY_SCOPE_AGENT);
        old = __shfl(old, 0, 64);
        if (old == 1) {                               // second arrival: partner done
            const float* sp = part + (srow * 2 + (side ^ 1)) * KNN;
#pragma unroll
            for (int k = 0; k < KNN; ++k)
                insert_t(arr, __hip_atomic_load(&sp[k], __ATOMIC_RELAXED,
                                                __HIP_MEMORY_SCOPE_AGENT));
            const int orow = perm[srow];              // original row id
            finalize_row(arr, px, py, pz, orow, lane, kmaxA, kminA, acc);
        }
    }
}

// K2: output, one element per thread.
__global__ __launch_bounds__(256) void out_elem_kernel(
    const float* __restrict__ kmaxA, const float* __restrict__ kminA,
    const float* __restrict__ acc,
    const float* __restrict__ w, const float* __restrict__ gamma,
    const float* __restrict__ beta, float* __restrict__ out)
{
    const int T = blockIdx.x * 256 + threadIdx.x;    // (b*16+c)*NPTS+n
    const int n  = T & (NPTS - 1);
    const int bc = T >> 13;
    const int c  = bc & 15;
    const int b  = bc >> 4;
    const float mu  = acc[0] * (1.0f / MTOTF);
    float var = acc[1] * (1.0f / MTOTF) - mu * mu;
    var = fmaxf(var, 0.f);
    const float wc = w[c];
    const float a  = gamma[c] * wc * rsqrtf(wc * wc * var + 1e-5f);
    const float d  = beta[c] - a * mu;               // conv bias cancels inside BN
    const float km = (a >= 0.f) ? kmaxA[b * NPTS + n] : kminA[b * NPTS + n];
    float v = a * km + d;
    v = (v >= 0.f) ? v : 0.2f * v;
    out[T] = v;
}

// ===================== fallback path (small ws; verified R1 structure) ========

__global__ __launch_bounds__(256) void prep_kernel(
    const float* __restrict__ x, float4* __restrict__ tile4, float* __restrict__ acc)
{
    const int i = blockIdx.x * 256 + threadIdx.x;
    const int b = i >> 13;
    const int m = i & (NPTS - 1);
    const float* xb = x + b * 3 * NPTS;
    const float qx = xb[m], qy = xb[NPTS + m], qz = xb[2 * NPTS + m];
    tile4[i] = make_float4(qx, qy, qz, -0.5f * (qx * qx + qy * qy + qz * qz));
    if (i < 2) acc[i] = 0.f;
}

__global__ __launch_bounds__(BLK, 8) void knn_kernel(
    const float* __restrict__ x, const float4* __restrict__ tile4,
    float* __restrict__ kmaxA, float* __restrict__ kminA, float* __restrict__ acc)
{
    __shared__ float shmem[(WPB - 1) * 64 * LSTR];
    __shared__ unsigned threshS[64];

    const int tid  = threadIdx.x;
    const int lane = tid & 63;
    const int wave = __builtin_amdgcn_readfirstlane(tid >> 6);
    const int rowBase = blockIdx.x * 64;
    const int row  = rowBase + lane;
    const int b    = rowBase >> 13;
    const int n    = row & (NPTS - 1);
    const float* xb = x + b * 3 * NPTS;
    const float px = xb[n];
    const float py = xb[NPTS + n];
    const float pz = xb[2 * NPTS + n];

    if (tid < 64) threshS[tid] = enc_f(NEG_INF);

    float arr[KNN];
#pragma unroll
    for (int j = 0; j < KNN; ++j) arr[j] = NEG_INF;
    float* bufw = shmem + wave * (CAP * 64);
    int cnt = 0;
    __syncthreads();

    const float4* __restrict__ tp = tile4 + b * NPTS + wave * SLICE;
    float th = NEG_INF;
    for (int c = 0; c < SLICE / 32; ++c) {
        th = dec_f(*(volatile unsigned*)(threshS + lane));
        const float4* tq = tp + c * 32;
        for (int g = 0; g < 8; ++g) {
#pragma unroll
            for (int u = 0; u < 4; ++u) {
                const float4 q = tq[g * 4 + u];
                const float t = fmaf(q.x, px, fmaf(q.y, py, fmaf(q.z, pz, q.w)));
                if (t > th) { bufw[cnt * 64 + lane] = t; ++cnt; }
            }
            if (__any(cnt > CAP - 4)) {
                flush_buf(arr, cnt, bufw, lane, threshS);
                th = dec_f(*(volatile unsigned*)(threshS + lane));
            }
        }
    }
    if (__any(cnt > 0)) flush_buf(arr, cnt, bufw, lane, threshS);
    __syncthreads();

    if (wave > 0) {
        float* dst = shmem + ((wave - 1) * 64 + lane) * LSTR;
#pragma unroll
        for (int j = 0; j < KNN; ++j) dst[j] = arr[j];
    }
    __syncthreads();

    if (wave == 0) {
        for (int wsrc = 0; wsrc < WPB - 1; ++wsrc) {
            const float* src = shmem + (wsrc * 64 + lane) * LSTR;
#pragma unroll
            for (int k = 0; k < KNN; ++k) insert_t(arr, src[k]);
        }
        finalize_row(arr, px, py, pz, row, lane, kmaxA, kminA, acc);
    }
}

__global__ __launch_bounds__(BLK) void knn_kernel_lds(
    const float* __restrict__ x,
    float* __restrict__ kmaxA, float* __restrict__ kminA, float* __restrict__ acc)
{
    __shared__ float4 tile[2048];
    __shared__ float  lists[(WPB - 1) * 64 * LSTR];

    const int tid  = threadIdx.x;
    const int lane = tid & 63;
    const int wave = tid >> 6;
    const int rowBase = blockIdx.x * 64;
    const int row  = rowBase + lane;
    const int b    = rowBase >> 13;
    const int n    = row & (NPTS - 1);
    const float* xb = x + b * 3 * NPTS;
    const float px = xb[n];
    const float py = xb[NPTS + n];
    const float pz = xb[2 * NPTS + n];

    float arr[KNN];
#pragma unroll
    for (int j = 0; j < KNN; ++j) arr[j] = NEG_INF;

    for (int t0 = 0; t0 < NPTS; t0 += 2048) {
        __syncthreads();
        const int i4 = tid * 4;
        const float4 qx4 = *(const float4*)(xb + t0 + i4);
        const float4 qy4 = *(const float4*)(xb + NPTS + t0 + i4);
        const float4 qz4 = *(const float4*)(xb + 2 * NPTS + t0 + i4);
        tile[i4 + 0] = make_float4(qx4.x, qy4.x, qz4.x, -0.5f * (qx4.x*qx4.x + qy4.x*qy4.x + qz4.x*qz4.x));
        tile[i4 + 1] = make_float4(qx4.y, qy4.y, qz4.y, -0.5f * (qx4.y*qx4.y + qy4.y*qy4.y + qz4.y*qz4.y));
        tile[i4 + 2] = make_float4(qx4.z, qy4.z, qz4.z, -0.5f * (qx4.z*qx4.z + qy4.z*qy4.z + qz4.z*qz4.z));
        tile[i4 + 3] = make_float4(qx4.w, qy4.w, qz4.w, -0.5f * (qx4.w*qx4.w + qy4.w*qy4.w + qz4.w*qz4.w));
        __syncthreads();
        const float4* basep = tile + wave * 256;
#pragma unroll 4
        for (int i = 0; i < 256; ++i) {
            const float4 q = basep[i];
            float t = fmaf(q.x, px, fmaf(q.y, py, fmaf(q.z, pz, q.w)));
            insert_t(arr, t);
        }
    }
    __syncthreads();

    if (wave > 0) {
        float* dst = lists + ((wave - 1) * 64 + lane) * LSTR;
#pragma unroll
        for (int j = 0; j < KNN; ++j) dst[j] = arr[j];
    }
    __syncthreads();

    if (wave == 0) {
        for (int wsrc = 0; wsrc < WPB - 1; ++wsrc) {
            const float* src = lists + (wsrc * 64 + lane) * LSTR;
#pragma unroll
            for (int k = 0; k < KNN; ++k) insert_t(arr, src[k]);
        }
        finalize_row(arr, px, py, pz, row, lane, kmaxA, kminA, acc);
    }
}

__global__ __launch_bounds__(256) void out_kernel(
    const float* __restrict__ kmaxA, const float* __restrict__ kminA,
    const float* __restrict__ acc,
    const float* __restrict__ w, const float* __restrict__ gamma,
    const float* __restrict__ beta, float* __restrict__ out)
{
    const int r = blockIdx.x * 256 + threadIdx.x;
    const int b = r >> 13;
    const int n = r & (NPTS - 1);
    const float mu  = acc[0] * (1.0f / MTOTF);
    float var = acc[1] * (1.0f / MTOTF) - mu * mu;
    var = fmaxf(var, 0.f);
    const float kmax = kmaxA[r];
    const float kmin = kminA[r];
#pragma unroll
    for (int c = 0; c < 16; ++c) {
        const float wc = w[c];
        const float a = gamma[c] * wc * rsqrtf(wc * wc * var + 1e-5f);
        const float d = beta[c] - a * mu;
        float v = a * (a >= 0.f ? kmax : kmin) + d;
        v = (v >= 0.f) ? v : 0.2f * v;
        out[(b * 16 + c) * NPTS + n] = v;
    }
}

extern "C" void kernel_launch(void* const* d_in, const int* in_sizes, int n_in,
                              void* d_out, int out_size, void* d_ws, size_t ws_size,
                              hipStream_t stream)
{
    const float* x     = (const float*)d_in[0];
    const float* w     = (const float*)d_in[1];
    const float* gamma = (const float*)d_in[3];
    const float* beta  = (const float*)d_in[4];
    float* out = (float*)d_out;
    float* ws  = (float*)d_ws;

    float* kmaxA = ws;                                // NROWS
    float* kminA = ws + NROWS;                        // NROWS
    float* acc   = ws + 2 * NROWS;                    // 2 (+2 pad)
    float4* sorted4 = (float4*)(ws + 2 * NROWS + 4);  // NROWS float4, 16B-aligned
    int*   perm  = (int*)(ws + (2 * NROWS + 4) + 4 * NROWS);   // NROWS ints
    float* part  = (float*)(perm + NROWS);            // NROWS*2*KNN floats
    int*   ticket = (int*)(part + (size_t)NROWS * 2 * KNN);    // NGROUPS ints

    const size_t need_tile   = (size_t)(2 * NROWS + 4) * 4 + (size_t)NROWS * 16;
    const size_t need_sorted = need_tile + (size_t)NROWS * 4
                               + (size_t)NROWS * 2 * KNN * 4 + (size_t)NGROUPS * 4;

    if (ws_size >= need_sorted) {
        sort_kernel<<<NB, 1024, 0, stream>>>(x, sorted4, perm, acc, ticket);
        knn_sorted_kernel<<<NGRID, BLK, 0, stream>>>(sorted4, perm, part, ticket,
                                                     kmaxA, kminA, acc);
        out_elem_kernel<<<(16 * NROWS) / 256, 256, 0, stream>>>(
            kmaxA, kminA, acc, w, gamma, beta, out);
    } else if (ws_size >= need_tile) {
        float4* tile4 = sorted4;
        prep_kernel<<<NROWS / 256, 256, 0, stream>>>(x, tile4, acc);
        knn_kernel<<<NROWS / 64, BLK, 0, stream>>>(x, tile4, kmaxA, kminA, acc);
        out_kernel<<<NROWS / 256, 256, 0, stream>>>(kmaxA, kminA, acc, w, gamma, beta, out);
    } else {
        prep_kernel<<<1, 256, 0, stream>>>(x, sorted4, acc);    // only zeroes acc
        knn_kernel_lds<<<NROWS / 64, BLK, 0, stream>>>(x, kmaxA, kminA, acc);
        out_kernel<<<NROWS / 256, 256, 0, stream>>>(kmaxA, kminA, acc, w, gamma, beta, out);
    }
}

// Round 12
// 182.987 us; speedup vs baseline: 1.3420x; 1.3420x over previous
//
#include <hip/hip_runtime.h>
#include <stdint.h>

#define NPTS  8192
#define NB    4
#define KNN   20
#define NROWS (NB * NPTS)        // 32768
#define NGROUPS (NROWS / 64)     // 512 row-groups
#define MTOTF 655360.0f          // NROWS * KNN
#define WPB   8                  // waves per block; all waves share the same 64 rows
#define BLK   (WPB * 64)         // 512 threads
#define SLICE (NPTS / WPB)       // 1024 candidates per wave (round-1 fallback)
#define HALF  (NPTS / 2)         // 4096 candidates per split block
#define SLICE2 (HALF / WPB)      // 512 candidates per wave
#define LSTR  (KNN + 1)          // padded merge-list stride
#define CAP   12                 // round-1 fallback push-buffer slots
#define CAP2  16                 // split push-buffer slots
#define NGRID (2 * NGROUPS)      // 1024 blocks = 4/CU
#define NEG_INF -3.0e38f

__device__ __forceinline__ float med3f(float a, float b, float c) {
    return __builtin_amdgcn_fmed3f(a, b, c);
}

// Monotone float<->uint encoding so LDS atomicMax works as float-max (any sign).
__device__ __forceinline__ unsigned enc_f(float f) {
    unsigned u = __float_as_uint(f);
    return (u & 0x80000000u) ? ~u : (u | 0x80000000u);
}
__device__ __forceinline__ float dec_f(unsigned u) {
    return __uint_as_float((u & 0x80000000u) ? (u & 0x7fffffffu) : ~u);
}

// Insert t into descending top-KNN list (arr[0] = largest t = nearest point).
// Dropping off the bottom is always exact: 20 larger witnesses exist.
__device__ __forceinline__ void insert_t(float arr[KNN], float t) {
#pragma unroll
    for (int j = KNN - 1; j > 0; --j) arr[j] = med3f(t, arr[j - 1], arr[j]);
    arr[0] = fmaxf(arr[0], t);
}

// ---- round-1 fallback flush: fixed CAP, padded ----
__device__ __forceinline__ void flush_buf(float arr[KNN], int& cnt,
    const float* bufw, int lane, unsigned* threshS) {
#pragma unroll
    for (int s = 0; s < CAP; ++s) {
        const float v = bufw[s * 64 + lane];
        insert_t(arr, (s < cnt) ? v : NEG_INF);
    }
    cnt = 0;
    atomicMax(&threshS[lane], enc_f(arr[KNN - 1]));
}

// ---- chunk-skippable flush (4 slots per uniform test), verified in R2/R8 ----
__device__ __forceinline__ void flush_dyn(float arr[KNN], int& cnt,
    const float* bufw, int lane, unsigned* threshS) {
#pragma unroll
    for (int s0 = 0; s0 < CAP2; s0 += 4) {
        if (__any(cnt > s0)) {
#pragma unroll
            for (int s = s0; s < s0 + 4; ++s) {
                const float v = bufw[s * 64 + lane];
                insert_t(arr, (s < cnt) ? v : NEG_INF);
            }
        }
    }
    cnt = 0;
    atomicMax(&threshS[lane], enc_f(arr[KNN - 1]));
}

// Shared tail: caller holds merged descending-t list for output row `row`.
// t = p.q - |q|^2/2, d2 = |p|^2 - 2t  (arr[0] = largest t = nearest).
__device__ __forceinline__ void finalize_row(
    float arr[KNN], float px, float py, float pz, int row, int lane,
    float* __restrict__ kmaxA, float* __restrict__ kminA, float* __restrict__ acc)
{
    const float pn2 = px * px + py * py + pz * pz;
    float sum = 0.f, sum2 = 0.f, dmin = 0.f, dmax = 0.f;
#pragma unroll
    for (int k = 0; k < KNN; ++k) {
        float d2 = fmaxf(fmaf(-2.f, arr[k], pn2), 0.f);
        float d = sqrtf(d2);
        sum += d; sum2 += d2;
        if (k == 0) dmin = d;
        dmax = d;
    }
    kmaxA[row] = dmax;
    kminA[row] = dmin;
#pragma unroll
    for (int o = 32; o; o >>= 1) {
        sum  += __shfl_down(sum,  o, 64);
        sum2 += __shfl_down(sum2, o, 64);
    }
    if (lane == 0) { atomicAdd(acc, sum); atomicAdd(acc + 1, sum2); }
}

// Prep: tile4[i] = (qx,qy,qz,-|q|^2/2); zero acc and the merge tickets.
__global__ __launch_bounds__(256) void prep_kernel(
    const float* __restrict__ x, float4* __restrict__ tile4,
    float* __restrict__ acc, int* __restrict__ ticket)
{
    const int i = blockIdx.x * 256 + threadIdx.x;    // 0..32767
    const int b = i >> 13;
    const int m = i & (NPTS - 1);
    const float* xb = x + b * 3 * NPTS;
    const float qx = xb[m], qy = xb[NPTS + m], qz = xb[2 * NPTS + m];
    tile4[i] = make_float4(qx, qy, qz, -0.5f * (qx * qx + qy * qy + qz * qz));
    if (i < 2) acc[i] = 0.f;
    if (ticket && i < NGROUPS) ticket[i] = 0;
}

// K1 (main): R8-verified half-scan + tree merge + sc1 last-block merge,
// with ONE change: the scan loop prefetches the NEXT 4-candidate group into
// registers (wave-uniform -> SGPRs, no VGPR cost) before processing the
// current group, covering the s_load L2 latency (~200cy) that the R11
// analysis identified as the real bottleneck (true VALU busy ~35% after
// correcting for the gfx94x-formula 2x overstatement).
__global__ __launch_bounds__(BLK, 8) void knn_fused_kernel(
    const float* __restrict__ x, const float4* __restrict__ tile4,
    float* __restrict__ part, int* __restrict__ ticket,
    float* __restrict__ kmaxA, float* __restrict__ kminA, float* __restrict__ acc)
{
    // 32 KB push buffers; tree-merge lists (4*64*21*4 = 21504 B) alias them.
    __shared__ float shmem[WPB * CAP2 * 64];
    __shared__ unsigned threshS[64];

    const int tid  = threadIdx.x;
    const int lane = tid & 63;
    const int wave = __builtin_amdgcn_readfirstlane(tid >> 6);
    const int rb   = blockIdx.x >> 1;        // row-group 0..511
    const int half = blockIdx.x & 1;         // candidate half
    const int rowBase = rb * 64;
    const int row  = rowBase + lane;
    const int b    = rowBase >> 13;
    const int n    = row & (NPTS - 1);
    const float* xb = x + b * 3 * NPTS;
    const float px = xb[n];
    const float py = xb[NPTS + n];
    const float pz = xb[2 * NPTS + n];

    if (tid < 64) threshS[tid] = enc_f(NEG_INF);

    float arr[KNN];
#pragma unroll
    for (int j = 0; j < KNN; ++j) arr[j] = NEG_INF;
    float* bufw = shmem + wave * (CAP2 * 64);
    __syncthreads();

    const float4* __restrict__ tp = tile4 + b * NPTS + half * HALF + wave * SLICE2;

    // Warm-up: private ladder over first 32; publish real 20-of-32 threshold.
#pragma unroll 8
    for (int i = 0; i < 32; ++i) {
        const float4 q = tp[i];
        insert_t(arr, fmaf(q.x, px, fmaf(q.y, py, fmaf(q.z, pz, q.w))));
    }
    atomicMax(&threshS[lane], enc_f(arr[KNN - 1]));

    int cnt = 0;
    for (int c = 1; c < SLICE2 / 32; ++c) {
        float th = dec_f(*(volatile unsigned*)(threshS + lane));
        const float4* tq = tp + c * 32;
        float4 qa[4];
#pragma unroll
        for (int u = 0; u < 4; ++u) qa[u] = tq[u];       // prefetch group 0
#pragma unroll
        for (int g = 0; g < 8; ++g) {
            float4 qb[4];
            if (g < 7) {                                  // prefetch group g+1
#pragma unroll
                for (int u = 0; u < 4; ++u) qb[u] = tq[g * 4 + 4 + u];
            } else {
#pragma unroll
                for (int u = 0; u < 4; ++u) qb[u] = make_float4(0.f, 0.f, 0.f, 0.f);
            }
#pragma unroll
            for (int u = 0; u < 4; ++u) {                 // process group g
                const float t = fmaf(qa[u].x, px,
                                 fmaf(qa[u].y, py, fmaf(qa[u].z, pz, qa[u].w)));
                bufw[cnt * 64 + lane] = t;                // always-store (no branch)
                cnt += (t > th);
            }
            if (__any(cnt > CAP2 - 4)) {
                flush_dyn(arr, cnt, bufw, lane, threshS);
                th = dec_f(*(volatile unsigned*)(threshS + lane));
            }
#pragma unroll
            for (int u = 0; u < 4; ++u) qa[u] = qb[u];
        }
    }
    if (__any(cnt > 0)) flush_dyn(arr, cnt, bufw, lane, threshS);
    __syncthreads();   // all push-buffer use done before aliased list writes

    // Tree merge (verified R4/R8): (0<-1)(2<-3)(4<-5)(6<-7) -> (0<-2)(4<-6) -> (0<-4)
    float* ml = shmem;
    if (wave & 1) {
        float* d = ml + (wave >> 1) * (64 * LSTR) + lane * LSTR;
#pragma unroll
        for (int k = 0; k < KNN; ++k) d[k] = arr[k];
    }
    __syncthreads();
    if (!(wave & 1)) {
        const float* s = ml + (wave >> 1) * (64 * LSTR) + lane * LSTR;
#pragma unroll
        for (int k = 0; k < KNN; ++k) insert_t(arr, s[k]);
    }
    __syncthreads();
    if (!(wave & 1) && (wave & 2)) {
        float* d = ml + (wave >> 2) * (64 * LSTR) + lane * LSTR;
#pragma unroll
        for (int k = 0; k < KNN; ++k) d[k] = arr[k];
    }
    __syncthreads();
    if ((wave & 3) == 0) {
        const float* s = ml + (wave >> 2) * (64 * LSTR) + lane * LSTR;
#pragma unroll
        for (int k = 0; k < KNN; ++k) insert_t(arr, s[k]);
    }
    __syncthreads();
    if (wave == 4) {
        float* d = ml + lane * LSTR;
#pragma unroll
        for (int k = 0; k < KNN; ++k) d[k] = arr[k];
    }
    __syncthreads();
    if (wave == 0) {
        const float* s = ml + lane * LSTR;
#pragma unroll
        for (int k = 0; k < KNN; ++k) insert_t(arr, s[k]);

        // publish my sorted partial list: agent-coherent relaxed stores (sc1),
        // NO fence -> no wbl2/inv -> co-resident scanners keep their L2 set.
        float* dst = part + (row * 2 + half) * KNN;
#pragma unroll
        for (int k = 0; k < KNN; ++k)
            __hip_atomic_store(&dst[k], arr[k], __ATOMIC_RELAXED,
                               __HIP_MEMORY_SCOPE_AGENT);
        // wave-local wait: my sc1 stores are at the coherent point before the
        // ticket bump becomes visible.
        asm volatile("s_waitcnt vmcnt(0)" ::: "memory");

        int old = 0;
        if (lane == 0)
            old = __hip_atomic_fetch_add(&ticket[rb], 1, __ATOMIC_RELAXED,
                                         __HIP_MEMORY_SCOPE_AGENT);
        old = __shfl(old, 0, 64);
        if (old == 1) {                               // I'm second: partner done
            const float* srcp = part + (row * 2 + (half ^ 1)) * KNN;
#pragma unroll
            for (int k = 0; k < KNN; ++k) {
                const float v = __hip_atomic_load(&srcp[k], __ATOMIC_RELAXED,
                                                  __HIP_MEMORY_SCOPE_AGENT);
                insert_t(arr, v);
            }
            finalize_row(arr, px, py, pz, row, lane, kmaxA, kminA, acc);
        }
    }
}

// K2: output, one element per thread (8192 waves -> latency well hidden).
__global__ __launch_bounds__(256) void out_elem_kernel(
    const float* __restrict__ kmaxA, const float* __restrict__ kminA,
    const float* __restrict__ acc,
    const float* __restrict__ w, const float* __restrict__ gamma,
    const float* __restrict__ beta, float* __restrict__ out)
{
    const int T = blockIdx.x * 256 + threadIdx.x;    // 0..524287 = (b*16+c)*NPTS+n
    const int n  = T & (NPTS - 1);
    const int bc = T >> 13;
    const int c  = bc & 15;
    const int b  = bc >> 4;
    const float mu  = acc[0] * (1.0f / MTOTF);
    float var = acc[1] * (1.0f / MTOTF) - mu * mu;
    var = fmaxf(var, 0.f);
    const float wc = w[c];
    const float a  = gamma[c] * wc * rsqrtf(wc * wc * var + 1e-5f);
    const float d  = beta[c] - a * mu;               // conv bias cancels inside BN
    const float km = (a >= 0.f) ? kmaxA[b * NPTS + n] : kminA[b * NPTS + n];
    float v = a * km + d;
    v = (v >= 0.f) ? v : 0.2f * v;
    out[T] = v;
}

// ===================== fallback path (small ws; verified R1 structure) ========

__global__ __launch_bounds__(BLK, 8) void knn_kernel(
    const float* __restrict__ x, const float4* __restrict__ tile4,
    float* __restrict__ kmaxA, float* __restrict__ kminA, float* __restrict__ acc)
{
    __shared__ float shmem[(WPB - 1) * 64 * LSTR];
    __shared__ unsigned threshS[64];

    const int tid  = threadIdx.x;
    const int lane = tid & 63;
    const int wave = __builtin_amdgcn_readfirstlane(tid >> 6);
    const int rowBase = blockIdx.x * 64;
    const int row  = rowBase + lane;
    const int b    = rowBase >> 13;
    const int n    = row & (NPTS - 1);
    const float* xb = x + b * 3 * NPTS;
    const float px = xb[n];
    const float py = xb[NPTS + n];
    const float pz = xb[2 * NPTS + n];

    if (tid < 64) threshS[tid] = enc_f(NEG_INF);

    float arr[KNN];
#pragma unroll
    for (int j = 0; j < KNN; ++j) arr[j] = NEG_INF;
    float* bufw = shmem + wave * (CAP * 64);
    int cnt = 0;
    __syncthreads();

    const float4* __restrict__ tp = tile4 + b * NPTS + wave * SLICE;
    float th = NEG_INF;
    for (int c = 0; c < SLICE / 32; ++c) {
        th = dec_f(*(volatile unsigned*)(threshS + lane));
        const float4* tq = tp + c * 32;
        for (int g = 0; g < 8; ++g) {
#pragma unroll
            for (int u = 0; u < 4; ++u) {
                const float4 q = tq[g * 4 + u];
                const float t = fmaf(q.x, px, fmaf(q.y, py, fmaf(q.z, pz, q.w)));
                if (t > th) { bufw[cnt * 64 + lane] = t; ++cnt; }
            }
            if (__any(cnt > CAP - 4)) {
                flush_buf(arr, cnt, bufw, lane, threshS);
                th = dec_f(*(volatile unsigned*)(threshS + lane));
            }
        }
    }
    if (__any(cnt > 0)) flush_buf(arr, cnt, bufw, lane, threshS);
    __syncthreads();

    if (wave > 0) {
        float* dst = shmem + ((wave - 1) * 64 + lane) * LSTR;
#pragma unroll
        for (int j = 0; j < KNN; ++j) dst[j] = arr[j];
    }
    __syncthreads();

    if (wave == 0) {
        for (int wsrc = 0; wsrc < WPB - 1; ++wsrc) {
            const float* src = shmem + (wsrc * 64 + lane) * LSTR;
#pragma unroll
            for (int k = 0; k < KNN; ++k) insert_t(arr, src[k]);
        }
        finalize_row(arr, px, py, pz, row, lane, kmaxA, kminA, acc);
    }
}

__global__ __launch_bounds__(BLK) void knn_kernel_lds(
    const float* __restrict__ x,
    float* __restrict__ kmaxA, float* __restrict__ kminA, float* __restrict__ acc)
{
    __shared__ float4 tile[2048];
    __shared__ float  lists[(WPB - 1) * 64 * LSTR];

    const int tid  = threadIdx.x;
    const int lane = tid & 63;
    const int wave = tid >> 6;
    const int rowBase = blockIdx.x * 64;
    const int row  = rowBase + lane;
    const int b    = rowBase >> 13;
    const int n    = row & (NPTS - 1);
    const float* xb = x + b * 3 * NPTS;
    const float px = xb[n];
    const float py = xb[NPTS + n];
    const float pz = xb[2 * NPTS + n];

    float arr[KNN];
#pragma unroll
    for (int j = 0; j < KNN; ++j) arr[j] = NEG_INF;

    for (int t0 = 0; t0 < NPTS; t0 += 2048) {
        __syncthreads();
        const int i4 = tid * 4;
        const float4 qx4 = *(const float4*)(xb + t0 + i4);
        const float4 qy4 = *(const float4*)(xb + NPTS + t0 + i4);
        const float4 qz4 = *(const float4*)(xb + 2 * NPTS + t0 + i4);
        tile[i4 + 0] = make_float4(qx4.x, qy4.x, qz4.x, -0.5f * (qx4.x*qx4.x + qy4.x*qy4.x + qz4.x*qz4.x));
        tile[i4 + 1] = make_float4(qx4.y, qy4.y, qz4.y, -0.5f * (qx4.y*qx4.y + qy4.y*qy4.y + qz4.y*qz4.y));
        tile[i4 + 2] = make_float4(qx4.z, qy4.z, qz4.z, -0.5f * (qx4.z*qx4.z + qy4.z*qy4.z + qz4.z*qz4.z));
        tile[i4 + 3] = make_float4(qx4.w, qy4.w, qz4.w, -0.5f * (qx4.w*qx4.w + qy4.w*qy4.w + qz4.w*qz4.w));
        __syncthreads();
        const float4* basep = tile + wave * 256;
#pragma unroll 4
        for (int i = 0; i < 256; ++i) {
            const float4 q = basep[i];
            float t = fmaf(q.x, px, fmaf(q.y, py, fmaf(q.z, pz, q.w)));
            insert_t(arr, t);
        }
    }
    __syncthreads();

    if (wave > 0) {
        float* dst = lists + ((wave - 1) * 64 + lane) * LSTR;
#pragma unroll
        for (int j = 0; j < KNN; ++j) dst[j] = arr[j];
    }
    __syncthreads();

    if (wave == 0) {
        for (int wsrc = 0; wsrc < WPB - 1; ++wsrc) {
            const float* src = lists + (wsrc * 64 + lane) * LSTR;
#pragma unroll
            for (int k = 0; k < KNN; ++k) insert_t(arr, src[k]);
        }
        finalize_row(arr, px, py, pz, row, lane, kmaxA, kminA, acc);
    }
}

__global__ __launch_bounds__(256) void out_kernel(
    const float* __restrict__ kmaxA, const float* __restrict__ kminA,
    const float* __restrict__ acc,
    const float* __restrict__ w, const float* __restrict__ gamma,
    const float* __restrict__ beta, float* __restrict__ out)
{
    const int r = blockIdx.x * 256 + threadIdx.x;
    const int b = r >> 13;
    const int n = r & (NPTS - 1);
    const float mu  = acc[0] * (1.0f / MTOTF);
    float var = acc[1] * (1.0f / MTOTF) - mu * mu;
    var = fmaxf(var, 0.f);
    const float kmax = kmaxA[r];
    const float kmin = kminA[r];
#pragma unroll
    for (int c = 0; c < 16; ++c) {
        const float wc = w[c];
        const float a = gamma[c] * wc * rsqrtf(wc * wc * var + 1e-5f);
        const float d = beta[c] - a * mu;
        float v = a * (a >= 0.f ? kmax : kmin) + d;
        v = (v >= 0.f) ? v : 0.2f * v;
        out[(b * 16 + c) * NPTS + n] = v;
    }
}

extern "C" void kernel_launch(void* const* d_in, const int* in_sizes, int n_in,
                              void* d_out, int out_size, void* d_ws, size_t ws_size,
                              hipStream_t stream)
{
    const float* x     = (const float*)d_in[0];
    const float* w     = (const float*)d_in[1];
    const float* gamma = (const float*)d_in[3];
    const float* beta  = (const float*)d_in[4];
    float* out = (float*)d_out;
    float* ws  = (float*)d_ws;

    float* kmaxA = ws;                                // NROWS
    float* kminA = ws + NROWS;                        // NROWS
    float* acc   = ws + 2 * NROWS;                    // 2 (+2 pad)
    float4* tile4 = (float4*)(ws + 2 * NROWS + 4);    // NROWS float4, 16B-aligned
    float* part  = ws + (2 * NROWS + 4) + 4 * NROWS;  // NROWS*2*KNN floats
    int* ticket  = (int*)(part + (size_t)NROWS * 2 * KNN);   // NGROUPS ints
    const size_t need_tile  = (size_t)(2 * NROWS + 4) * 4 + (size_t)NROWS * 16;
    const size_t need_fused = need_tile + (size_t)NROWS * 2 * KNN * 4
                              + (size_t)NGROUPS * 4;

    if (ws_size >= need_fused) {
        prep_kernel<<<NROWS / 256, 256, 0, stream>>>(x, tile4, acc, ticket);
        knn_fused_kernel<<<NGRID, BLK, 0, stream>>>(x, tile4, part, ticket,
                                                    kmaxA, kminA, acc);
        out_elem_kernel<<<(16 * NROWS) / 256, 256, 0, stream>>>(
            kmaxA, kminA, acc, w, gamma, beta, out);
    } else if (ws_size >= need_tile) {
        prep_kernel<<<NROWS / 256, 256, 0, stream>>>(x, tile4, acc, nullptr);
        knn_kernel<<<NROWS / 64, BLK, 0, stream>>>(x, tile4, kmaxA, kminA, acc);
        out_kernel<<<NROWS / 256, 256, 0, stream>>>(kmaxA, kminA, acc, w, gamma, beta, out);
    } else {
        prep_kernel<<<1, 256, 0, stream>>>(x, tile4, acc, nullptr); // only zeroes acc
        knn_kernel_lds<<<NROWS / 64, BLK, 0, stream>>>(x, kmaxA, kminA, acc);
        out_kernel<<<NROWS / 256, 256, 0, stream>>>(kmaxA, kminA, acc, w, gamma, beta, out);
    }
}